// Round 4
// baseline (256.700 us; speedup 1.0000x reference)
//
#include <hip/hip_runtime.h>
#include <math.h>

// CapsNet dynamic routing, fused per-(batch, out_capsule) block. R4:
// - R3 body (scalarized, spill-free at VGPR=56, bank-conflict-free swizzle)
//   + __launch_bounds__(1024, 8) to force 8 waves/EU => 2 blocks/CU.
//   R3 at (1024,1) ran 1 block/CU (43% occ) despite LDS fitting 2 blocks;
//   R2 showed 89% occ is reachable at this LDS size. 56 regs <= 64 cap, so
//   no spills expected (tripwire: WRITE_SIZE must stay ~160 KB).
//
// u:      [256][1152][8]  f32
// weight: [1152][10][8][16] f32
// out v:  [256][10][16] f32

#define IC 1152
#define OC 10
#define ID 8
#define OD 16
#define NBATCH 256

// logical (i, m) -> LDS float index: (i<<4) + (((m>>2) ^ XS(i)) << 2) + (m&3)
// Bank analysis: Phase-A float4 writes 2-way (free), s-pass column reads
// 2-way, b-update b128 reads ~4-way worst -> measured 0 conflicts in R3.
#define XS(i) (((i) ^ ((i) >> 2)) & 3)

__global__ __launch_bounds__(1024, 8)
void caps_route_kernel(const float* __restrict__ u,
                       const float* __restrict__ W,
                       float* __restrict__ out) {
    extern __shared__ float smem[];
    float* uhat  = smem;                 // IC*16 = 18432 floats (73728 B)
    float* cexp  = uhat + IC * 16;       // IC
    float* red   = cexp + IC;            // 16 waves * 16 m
    float* wredA = red + 256;            // 16 (max partials)
    float* wredB = wredA + 16;           // 16 (sum partials)

    const int t    = threadIdx.x;
    const int lane = t & 63;
    const int wid  = t >> 6;
    const int bx   = blockIdx.x;

    // XCD-aware (b,j) mapping (perf heuristic: xcd = bx & 7).
    int x = bx & 7, sgrp = bx >> 3;
    int b, j;
    if (sgrp < 256) { j = x; b = sgrp; }
    else { int s2 = sgrp - 256; j = 8 + (x >> 2); b = ((x & 3) << 6) + s2; }

    // ---- Phase A: uhat[i][m] = sum_n u[b,i,n] * W[i,j,n,m] -> LDS ----
    {
        const int mq = t & 3;  // logical quad of the 16-m row
        for (int i = (t >> 2); i < IC; i += 256) {
            const float4* wrow = (const float4*)(W + (size_t)(i * OC + j) * 128);
            const float*  up   = u + (size_t)b * (IC * ID) + i * ID;
            const float4 ua = *(const float4*)up;
            const float4 ub = *(const float4*)(up + 4);
            float4 acc = {0.f, 0.f, 0.f, 0.f};
            float4 w4;
#define PHA_STEP(uu, widx)                                   \
            w4 = wrow[(widx) * 4 + mq];                      \
            acc.x += (uu) * w4.x; acc.y += (uu) * w4.y;      \
            acc.z += (uu) * w4.z; acc.w += (uu) * w4.w;
            PHA_STEP(ua.x, 0) PHA_STEP(ua.y, 1) PHA_STEP(ua.z, 2) PHA_STEP(ua.w, 3)
            PHA_STEP(ub.x, 4) PHA_STEP(ub.y, 5) PHA_STEP(ub.z, 6) PHA_STEP(ub.w, 7)
#undef PHA_STEP
            *(float4*)&uhat[(i << 4) + ((mq ^ XS(i)) << 2)] = acc;
        }
    }

    // routing logits in registers: thread t owns i0 = t, and i1 = t+1024 if t<128
    const bool has2 = (t < IC - 1024);
    float b0 = 0.f, b1 = 0.f;

    __syncthreads();  // B0: uhat ready

    const int sg  = t >> 4;   // s-pass row group (i = sg + 64k -> XS(i) == XS(sg))
    const int sm_ = t & 15;   // s-pass m
    const int soff = (((sm_ >> 2) ^ XS(sg)) << 2) + (sm_ & 3);

    for (int r = 0; r < 3; ++r) {
        float inv;  // 1 / sum(exp)
        if (r == 0) {
            inv = 1.0f / (float)IC;  // softmax(0) is exactly uniform
        } else {
            // ---- max over b (registers -> wave -> block) ----
            float lm = b0;
            if (has2) lm = fmaxf(lm, b1);
#pragma unroll
            for (int o = 32; o >= 1; o >>= 1) lm = fmaxf(lm, __shfl_xor(lm, o, 64));
            if (lane == 0) wredA[wid] = lm;
            __syncthreads();  // B1
            float mv = wredA[lane & 15];
#pragma unroll
            for (int o = 8; o >= 1; o >>= 1) mv = fmaxf(mv, __shfl_xor(mv, o, 16));
            const float bmax = mv;

            // ---- exp + sum ----
            float e0 = __expf(b0 - bmax);
            cexp[t] = e0;
            float ls = e0;
            if (has2) {
                float e1 = __expf(b1 - bmax);
                cexp[t + 1024] = e1;
                ls += e1;
            }
#pragma unroll
            for (int o = 32; o >= 1; o >>= 1) ls += __shfl_xor(ls, o, 64);
            if (lane == 0) wredB[wid] = ls;
            __syncthreads();  // B2 (also covers cexp writes)
            float sv = wredB[lane & 15];
#pragma unroll
            for (int o = 8; o >= 1; o >>= 1) sv += __shfl_xor(sv, o, 16);
            inv = 1.0f / sv;
        }

        // ---- s[m] = inv * sum_i c[i] * uhat[i][m] ----
        {
            float acc = 0.f;
            if (r == 0) {
#pragma unroll
                for (int k = 0; k < IC / 64; ++k)
                    acc += uhat[((sg + 64 * k) << 4) + soff];
            } else {
#pragma unroll
                for (int k = 0; k < IC / 64; ++k)
                    acc += cexp[sg + 64 * k] * uhat[((sg + 64 * k) << 4) + soff];
            }
            acc += __shfl_xor(acc, 16, 64);
            acc += __shfl_xor(acc, 32, 64);
            if (lane < 16) red[wid * 16 + sm_] = acc;
        }
        __syncthreads();  // B3

        // ---- finalize s + squash, redundantly per thread (m = lane&15) ----
        float smv = 0.f;
#pragma unroll
        for (int w = 0; w < 16; ++w) smv += red[w * 16 + (lane & 15)];
        smv *= inv;
        float p2 = smv * smv;
#pragma unroll
        for (int o = 8; o >= 1; o >>= 1) p2 += __shfl_xor(p2, o, 16);
        // squash scale: s2/(1+s2) / sqrt(s2+eps)
        const float sc = p2 / ((1.0f + p2) * sqrtf(p2 + 1e-8f));
        const float vm = smv * sc;

        if (r == 2) {
            if (t < 16) out[(size_t)(b * OC + j) * OD + t] = vm;
        } else {
            // gather full v[0..15] via width-16 shuffles (no LDS, no barrier)
            const float4 v4a = make_float4(__shfl(vm, 0, 16),  __shfl(vm, 1, 16),
                                           __shfl(vm, 2, 16),  __shfl(vm, 3, 16));
            const float4 v4b = make_float4(__shfl(vm, 4, 16),  __shfl(vm, 5, 16),
                                           __shfl(vm, 6, 16),  __shfl(vm, 7, 16));
            const float4 v4c = make_float4(__shfl(vm, 8, 16),  __shfl(vm, 9, 16),
                                           __shfl(vm, 10, 16), __shfl(vm, 11, 16));
            const float4 v4d = make_float4(__shfl(vm, 12, 16), __shfl(vm, 13, 16),
                                           __shfl(vm, 14, 16), __shfl(vm, 15, 16));
            // ---- b[i] += v . uhat[i][:] (register blog, swizzled b128 reads) ----
            float4 q;
#define BUP(i, dst)                                                          \
            q = *(const float4*)&uhat[((i) << 4) + ((0 ^ XS(i)) << 2)];      \
            dst += q.x * v4a.x + q.y * v4a.y + q.z * v4a.z + q.w * v4a.w;    \
            q = *(const float4*)&uhat[((i) << 4) + ((1 ^ XS(i)) << 2)];      \
            dst += q.x * v4b.x + q.y * v4b.y + q.z * v4b.z + q.w * v4b.w;    \
            q = *(const float4*)&uhat[((i) << 4) + ((2 ^ XS(i)) << 2)];      \
            dst += q.x * v4c.x + q.y * v4c.y + q.z * v4c.z + q.w * v4c.w;    \
            q = *(const float4*)&uhat[((i) << 4) + ((3 ^ XS(i)) << 2)];      \
            dst += q.x * v4d.x + q.y * v4d.y + q.z * v4d.z + q.w * v4d.w;
            BUP(t, b0)
            if (has2) { BUP(t + 1024, b1) }
#undef BUP
        }
    }
}

extern "C" void kernel_launch(void* const* d_in, const int* in_sizes, int n_in,
                              void* d_out, int out_size, void* d_ws, size_t ws_size,
                              hipStream_t stream) {
    const float* u = (const float*)d_in[0];
    const float* W = (const float*)d_in[1];
    float* out = (float*)d_out;

    const size_t shmem = (size_t)(IC * 16 + IC + 256 + 16 + 16) * sizeof(float);  // 79488 B
    hipFuncSetAttribute((const void*)caps_route_kernel,
                        hipFuncAttributeMaxDynamicSharedMemorySize, (int)shmem);

    caps_route_kernel<<<NBATCH * OC, 1024, shmem, stream>>>(u, W, out);
}

// Round 5
// 164.046 us; speedup vs baseline: 1.5648x; 1.5648x over previous
//
#include <hip/hip_runtime.h>
#include <math.h>

// CapsNet dynamic routing, fused per-(batch, out_capsule) block. R5:
// - 512-thread blocks (8 waves). Empirical rule from R2/R3/R4: usable arch
//   VGPR pool ~256/SIMD -> 8 waves/SIMD needs <=32 regs (spills), 4 waves/SIMD
//   needs <=64 (R3 ran 56 spill-free). With 512-thread blocks, 2 co-resident
//   blocks = 4 waves/SIMD at <=64 regs: spill-free cross-block overlap.
// - LDS 77.1 KB/block -> 2 blocks = 158 KB <= 160 KB.
// - s-pass vectorized to ds_read_b128 (logical m-quad per thread), ~3x fewer
//   LDS instructions than per-element b32.
// - __launch_bounds__(512, 4): cap VGPR at 64 (= need), no allocator squeeze.
//
// u:      [256][1152][8]  f32
// weight: [1152][10][8][16] f32
// out v:  [256][10][16] f32

#define IC 1152
#define OC 10
#define ID 8
#define OD 16
#define NBATCH 256

// logical (i, m) -> LDS float index: (i<<4) + (((m>>2) ^ XS(i)) << 2) + (m&3)
#define XS(i) (((i) ^ ((i) >> 2)) & 3)

__global__ __launch_bounds__(512, 4)
void caps_route_kernel(const float* __restrict__ u,
                       const float* __restrict__ W,
                       float* __restrict__ out) {
    extern __shared__ float smem[];
    float* uhat  = smem;                 // IC*16 = 18432 floats (73728 B)
    float* cexp  = uhat + IC * 16;       // IC (4608 B)
    float* red   = cexp + IC;            // 8 waves * 16 m (512 B)
    float* wredA = red + 128;            // 8 (pad 16)
    float* wredB = wredA + 16;           // 8 (pad 16)

    const int t    = threadIdx.x;
    const int lane = t & 63;
    const int wid  = t >> 6;             // 0..7
    const int bx   = blockIdx.x;

    // XCD-aware (b,j) mapping (perf heuristic: xcd = bx & 7).
    int x = bx & 7, sgrp = bx >> 3;
    int b, j;
    if (sgrp < 256) { j = x; b = sgrp; }
    else { int s2 = sgrp - 256; j = 8 + (x >> 2); b = ((x & 3) << 6) + s2; }

    // ---- Phase A: uhat[i][m] = sum_n u[b,i,n] * W[i,j,n,m] -> LDS ----
    {
        const int mq = t & 3;            // logical quad
        const int i0 = t >> 2;           // 0..127
#pragma unroll
        for (int k = 0; k < 9; ++k) {
            const int i = i0 + 128 * k;
            const float4* wrow = (const float4*)(W + (size_t)(i * OC + j) * 128);
            const float*  up   = u + (size_t)b * (IC * ID) + i * ID;
            const float4 ua = *(const float4*)up;
            const float4 ub = *(const float4*)(up + 4);
            float4 acc = {0.f, 0.f, 0.f, 0.f};
            float4 w4;
#define PHA_STEP(uu, widx)                                   \
            w4 = wrow[(widx) * 4 + mq];                      \
            acc.x += (uu) * w4.x; acc.y += (uu) * w4.y;      \
            acc.z += (uu) * w4.z; acc.w += (uu) * w4.w;
            PHA_STEP(ua.x, 0) PHA_STEP(ua.y, 1) PHA_STEP(ua.z, 2) PHA_STEP(ua.w, 3)
            PHA_STEP(ub.x, 4) PHA_STEP(ub.y, 5) PHA_STEP(ub.z, 6) PHA_STEP(ub.w, 7)
#undef PHA_STEP
            *(float4*)&uhat[(i << 4) + ((mq ^ XS(i)) << 2)] = acc;
        }
    }

    // routing logits in registers: thread t owns i = t, t+512, (t<128: t+1024)
    const bool has3 = (t < IC - 1024);
    float b0 = 0.f, b1 = 0.f, b2 = 0.f;

    __syncthreads();  // B0: uhat ready

    const int sq = t & 3;     // s-pass logical m-quad
    const int si = t >> 2;    // s-pass row base, 0..127

    for (int r = 0; r < 3; ++r) {
        float inv;  // 1 / sum(exp)
        if (r == 0) {
            inv = 1.0f / (float)IC;  // softmax(0) is exactly uniform
        } else {
            // ---- max over b (registers -> wave -> block) ----
            float lm = fmaxf(b0, b1);
            if (has3) lm = fmaxf(lm, b2);
#pragma unroll
            for (int o = 32; o >= 1; o >>= 1) lm = fmaxf(lm, __shfl_xor(lm, o, 64));
            if (lane == 0) wredA[wid] = lm;
            __syncthreads();  // B1
            float mv = wredA[lane & 7];
#pragma unroll
            for (int o = 4; o >= 1; o >>= 1) mv = fmaxf(mv, __shfl_xor(mv, o, 8));
            const float bmax = mv;

            // ---- exp + sum ----
            float e0 = __expf(b0 - bmax);
            float e1 = __expf(b1 - bmax);
            cexp[t] = e0;
            cexp[t + 512] = e1;
            float ls = e0 + e1;
            if (has3) {
                float e2 = __expf(b2 - bmax);
                cexp[t + 1024] = e2;
                ls += e2;
            }
#pragma unroll
            for (int o = 32; o >= 1; o >>= 1) ls += __shfl_xor(ls, o, 64);
            if (lane == 0) wredB[wid] = ls;
            __syncthreads();  // B2 (also covers cexp writes)
            float sv = wredB[lane & 7];
#pragma unroll
            for (int o = 4; o >= 1; o >>= 1) sv += __shfl_xor(sv, o, 8);
            inv = 1.0f / sv;
        }

        // ---- s[4q..4q+3] partial = sum_i c[i] * uhat[i][quad q] (b128 reads) ----
        {
            float4 acc = {0.f, 0.f, 0.f, 0.f};
#pragma unroll
            for (int k = 0; k < 9; ++k) {
                const int i = si + 128 * k;
                const float4 qv = *(const float4*)&uhat[(i << 4) + ((sq ^ XS(i)) << 2)];
                if (r == 0) {
                    acc.x += qv.x; acc.y += qv.y; acc.z += qv.z; acc.w += qv.w;
                } else {
                    const float c = cexp[i];
                    acc.x += c * qv.x; acc.y += c * qv.y;
                    acc.z += c * qv.z; acc.w += c * qv.w;
                }
            }
            // reduce over the 16 i-subgroups within the wave (lanes strided 4)
#pragma unroll
            for (int o = 4; o <= 32; o <<= 1) {
                acc.x += __shfl_xor(acc.x, o, 64);
                acc.y += __shfl_xor(acc.y, o, 64);
                acc.z += __shfl_xor(acc.z, o, 64);
                acc.w += __shfl_xor(acc.w, o, 64);
            }
            if (lane < 4) *(float4*)&red[wid * 16 + (sq << 2)] = acc;
        }
        __syncthreads();  // B3

        // ---- finalize s + squash, redundantly per thread (m = lane&15) ----
        float smv = 0.f;
#pragma unroll
        for (int w = 0; w < 8; ++w) smv += red[w * 16 + (lane & 15)];
        smv *= inv;
        float p2 = smv * smv;
#pragma unroll
        for (int o = 8; o >= 1; o >>= 1) p2 += __shfl_xor(p2, o, 16);
        // squash scale: s2/(1+s2) / sqrt(s2+eps)
        const float sc = p2 / ((1.0f + p2) * sqrtf(p2 + 1e-8f));
        const float vm = smv * sc;

        if (r == 2) {
            if (t < 16) out[(size_t)(b * OC + j) * OD + t] = vm;
        } else {
            // gather full v[0..15] via width-16 shuffles (no LDS, no barrier)
            const float4 v4a = make_float4(__shfl(vm, 0, 16),  __shfl(vm, 1, 16),
                                           __shfl(vm, 2, 16),  __shfl(vm, 3, 16));
            const float4 v4b = make_float4(__shfl(vm, 4, 16),  __shfl(vm, 5, 16),
                                           __shfl(vm, 6, 16),  __shfl(vm, 7, 16));
            const float4 v4c = make_float4(__shfl(vm, 8, 16),  __shfl(vm, 9, 16),
                                           __shfl(vm, 10, 16), __shfl(vm, 11, 16));
            const float4 v4d = make_float4(__shfl(vm, 12, 16), __shfl(vm, 13, 16),
                                           __shfl(vm, 14, 16), __shfl(vm, 15, 16));
            // ---- b[i] += v . uhat[i][:] (register blog, swizzled b128 reads) ----
            float4 q;
#define BUP(i, dst)                                                          \
            q = *(const float4*)&uhat[((i) << 4) + ((0 ^ XS(i)) << 2)];      \
            dst += q.x * v4a.x + q.y * v4a.y + q.z * v4a.z + q.w * v4a.w;    \
            q = *(const float4*)&uhat[((i) << 4) + ((1 ^ XS(i)) << 2)];      \
            dst += q.x * v4b.x + q.y * v4b.y + q.z * v4b.z + q.w * v4b.w;    \
            q = *(const float4*)&uhat[((i) << 4) + ((2 ^ XS(i)) << 2)];      \
            dst += q.x * v4c.x + q.y * v4c.y + q.z * v4c.z + q.w * v4c.w;    \
            q = *(const float4*)&uhat[((i) << 4) + ((3 ^ XS(i)) << 2)];      \
            dst += q.x * v4d.x + q.y * v4d.y + q.z * v4d.z + q.w * v4d.w;
            BUP(t, b0)
            BUP(t + 512, b1)
            if (has3) { BUP(t + 1024, b2) }
#undef BUP
        }
    }
}

extern "C" void kernel_launch(void* const* d_in, const int* in_sizes, int n_in,
                              void* d_out, int out_size, void* d_ws, size_t ws_size,
                              hipStream_t stream) {
    const float* u = (const float*)d_in[0];
    const float* W = (const float*)d_in[1];
    float* out = (float*)d_out;

    const size_t shmem = (size_t)(IC * 16 + IC + 128 + 16 + 16) * sizeof(float);  // 78976 B
    hipFuncSetAttribute((const void*)caps_route_kernel,
                        hipFuncAttributeMaxDynamicSharedMemorySize, (int)shmem);

    caps_route_kernel<<<NBATCH * OC, 512, shmem, stream>>>(u, W, out);
}

// Round 6
// 144.666 us; speedup vs baseline: 1.7744x; 1.1340x over previous
//
#include <hip/hip_runtime.h>
#include <hip/hip_bf16.h>
#include <math.h>

// CapsNet dynamic routing. R6: 2 batches per block, bf16 uhat in LDS.
// - Each block owns (j, batch-pair): every W w4 load feeds FMAs for BOTH
//   batches -> W L2 traffic halves (1.5 GB -> 755 MB, ~22 us L2 floor) and
//   total load-latency exposure halves (1280 blocks x same loads).
// - uhat stored bf16 (2 tiles x 36.9 KB) + bf16 cexp -> LDS 77.1 KB/block,
//   still 2 blocks/CU. Routing: waves 0-3 = batch 0, waves 4-7 = batch 1.
// - __launch_bounds__(512, 2): R5 showed the allocator snaps to tier buckets
//   and spills at a 64 cap (72 MB scratch). Cap 256 lets natural ~80-100
//   regs allocate spill-free; HW still fits 2 blocks (4 waves/SIMD x <=128).
// - softmax max-subtraction dropped (|b| <= ~50, e^b safe in f32): 6 barriers.
// - half-XOR swizzle phys_half = h ^ ((i>>2)&1): Phase-A writes + s-pass b64
//   reads bank-optimal (4/bank), b-update b128 2-way (free).
//
// u: [256][1152][8] f32; weight: [1152][10][8][16] f32; out: [256][10][16] f32

#define IC 1152
#define OC 10
#define OD 16
#define NB 256

__device__ __forceinline__ float bf_lo(unsigned w) { return __uint_as_float(w << 16); }
__device__ __forceinline__ float bf_hi(unsigned w) { return __uint_as_float(w & 0xFFFF0000u); }
__device__ __forceinline__ unsigned pack2(float a, float b) {
    __hip_bfloat162 h = __float22bfloat162_rn(make_float2(a, b));
    return *(unsigned*)&h;
}
__device__ __forceinline__ unsigned short pack1(float a) {
    __hip_bfloat16 h = __float2bfloat16(a);
    return *(unsigned short*)&h;
}

__global__ __launch_bounds__(512, 2)
void caps_route_kernel(const float* __restrict__ u,
                       const float* __restrict__ W,
                       float* __restrict__ out) {
    extern __shared__ unsigned smem_u[];
    unsigned* uh = smem_u;                                 // 2 tiles * 1152 rows * 8 dwords (73728 B)
    unsigned short* ce = (unsigned short*)(uh + 2 * IC * 8);  // 2*1152 bf16 (4608 B)
    float* red  = (float*)(ce + 2 * IC);                   // 2 halves * 4 waves * 16 m (512 B)
    float* wred = red + 128;                               // 16 f (sum partials)

    const int t  = threadIdx.x;
    const int bx = blockIdx.x;

    // XCD-aware (j, batch-pair) mapping (xcd = bx & 7 heuristic).
    int x = bx & 7, sg = bx >> 3;
    int j, p;
    if (sg < 128) { j = x; p = sg; }
    else { int s2 = sg - 128; j = 8 + (x >> 2); p = ((x & 3) << 5) + s2; }
    const int bb = p * 2;  // batches bb, bb+1

    // ---- Phase A: uhat[B][i][m] = sum_n u[bb+B,i,n] * W[i,j,n,m] -> LDS bf16 ----
    {
        const int q  = t & 3;            // m-quad
        const int i0 = t >> 2;           // 0..127; (i>>2)&1 is k-independent
        const int pb = (((q >> 1) ^ ((i0 >> 2) & 1)) << 2) + ((q & 1) << 1);
        const float* u0p = u + (size_t)bb * (IC * 8);
#pragma unroll 3
        for (int k = 0; k < 9; ++k) {
            const int i = i0 + 128 * k;
            const float4* wrow = (const float4*)(W + ((size_t)(i * OC + j) << 7)) + q;
            const float4 ua0 = *(const float4*)(u0p + i * 8);
            const float4 ua1 = *(const float4*)(u0p + i * 8 + 4);
            const float4 ub0 = *(const float4*)(u0p + IC * 8 + i * 8);
            const float4 ub1 = *(const float4*)(u0p + IC * 8 + i * 8 + 4);
            float4 s0 = {0.f, 0.f, 0.f, 0.f}, s1 = {0.f, 0.f, 0.f, 0.f};
            float4 w4;
#define ST(ux, uy, n)                                                     \
            w4 = wrow[(n) * 4];                                           \
            s0.x += (ux) * w4.x; s0.y += (ux) * w4.y;                     \
            s0.z += (ux) * w4.z; s0.w += (ux) * w4.w;                     \
            s1.x += (uy) * w4.x; s1.y += (uy) * w4.y;                     \
            s1.z += (uy) * w4.z; s1.w += (uy) * w4.w;
            ST(ua0.x, ub0.x, 0) ST(ua0.y, ub0.y, 1) ST(ua0.z, ub0.z, 2) ST(ua0.w, ub0.w, 3)
            ST(ua1.x, ub1.x, 4) ST(ua1.y, ub1.y, 5) ST(ua1.z, ub1.z, 6) ST(ua1.w, ub1.w, 7)
#undef ST
            const int dst = (i << 3) + pb;
            *(uint2*)&uh[dst]            = make_uint2(pack2(s0.x, s0.y), pack2(s0.z, s0.w));
            *(uint2*)&uh[IC * 8 + dst]   = make_uint2(pack2(s1.x, s1.y), pack2(s1.z, s1.w));
        }
    }

    // ---- Routing: half-block per batch ----
    const int hb   = t >> 8;          // batch half
    const int tt   = t & 255;
    const int lane = t & 63;
    const int wv   = tt >> 6;         // wave within half, 0..3
    unsigned* uhT = uh + hb * (IC * 8);
    unsigned short* ceT = ce + hb * IC;
    const bool has5 = tt < (IC - 1024);

    float L0 = 0.f, L1 = 0.f, L2 = 0.f, L3 = 0.f, L4 = 0.f;  // logits, rows tt+256k

    __syncthreads();  // B0: uhat ready

    const int sq   = tt & 3;          // s-pass m-quad
    const int si   = tt >> 2;         // 0..63; rows si+64k -> (i>>2)&1 k-independent
    const int soff = (((sq >> 1) ^ ((si >> 2) & 1)) << 2) + ((sq & 1) << 1);
    const int swb  = (tt >> 2) & 1;   // b-update: phys half0 = logical half swb

    for (int r = 0; r < 3; ++r) {
        float inv;
        if (r == 0) {
            inv = 1.0f / (float)IC;   // softmax(0) exactly uniform
        } else {
            // exp (no max-sub: |b| bounded, f32 safe) + bf16 store + sum
            float e0 = __expf(L0), e1 = __expf(L1), e2 = __expf(L2), e3 = __expf(L3);
            ceT[tt]       = pack1(e0);
            ceT[tt + 256] = pack1(e1);
            ceT[tt + 512] = pack1(e2);
            ceT[tt + 768] = pack1(e3);
            float ls = (e0 + e1) + (e2 + e3);
            if (has5) { float e4 = __expf(L4); ceT[tt + 1024] = pack1(e4); ls += e4; }
#pragma unroll
            for (int o = 32; o >= 1; o >>= 1) ls += __shfl_xor(ls, o, 64);
            if (lane == 0) wred[hb * 4 + wv] = ls;
            __syncthreads();  // covers ce writes + wred
            inv = 1.0f / (wred[hb * 4] + wred[hb * 4 + 1] + wred[hb * 4 + 2] + wred[hb * 4 + 3]);
        }

        // ---- s-pass: quad partials over rows si+64k ----
        float4 acc = {0.f, 0.f, 0.f, 0.f};
        if (r == 0) {
#pragma unroll 6
            for (int k = 0; k < 18; ++k) {
                const int i = si + 64 * k;
                const uint2 d = *(const uint2*)&uhT[(i << 3) + soff];
                acc.x += bf_lo(d.x); acc.y += bf_hi(d.x);
                acc.z += bf_lo(d.y); acc.w += bf_hi(d.y);
            }
        } else {
#pragma unroll 6
            for (int k = 0; k < 18; ++k) {
                const int i = si + 64 * k;
                const uint2 d = *(const uint2*)&uhT[(i << 3) + soff];
                const float c = __uint_as_float(((unsigned)ceT[i]) << 16);
                acc.x += c * bf_lo(d.x); acc.y += c * bf_hi(d.x);
                acc.z += c * bf_lo(d.y); acc.w += c * bf_hi(d.y);
            }
        }
#pragma unroll
        for (int o = 4; o <= 32; o <<= 1) {
            acc.x += __shfl_xor(acc.x, o, 64);
            acc.y += __shfl_xor(acc.y, o, 64);
            acc.z += __shfl_xor(acc.z, o, 64);
            acc.w += __shfl_xor(acc.w, o, 64);
        }
        if (lane < 4) *(float4*)&red[hb * 64 + wv * 16 + (sq << 2)] = acc;
        __syncthreads();

        // ---- finalize s + squash, redundant per thread (m = tt&15) ----
        const int m = tt & 15;
        float smv = red[hb * 64 + m] + red[hb * 64 + 16 + m]
                  + red[hb * 64 + 32 + m] + red[hb * 64 + 48 + m];
        smv *= inv;
        float p2 = smv * smv;
#pragma unroll
        for (int o = 8; o >= 1; o >>= 1) p2 += __shfl_xor(p2, o, 16);
        const float sc = p2 / ((1.0f + p2) * sqrtf(p2 + 1e-8f));
        const float vm = smv * sc;

        if (r == 2) {
            if (tt < 16) out[((size_t)(bb + hb) * OC + j) * OD + tt] = vm;
        } else {
            // gather v via width-16 shuffles, pre-swapped for this thread's rows
            const float v0  = __shfl(vm, 0, 16),  v1  = __shfl(vm, 1, 16);
            const float v2  = __shfl(vm, 2, 16),  v3  = __shfl(vm, 3, 16);
            const float v4  = __shfl(vm, 4, 16),  v5  = __shfl(vm, 5, 16);
            const float v6  = __shfl(vm, 6, 16),  v7  = __shfl(vm, 7, 16);
            const float v8  = __shfl(vm, 8, 16),  v9  = __shfl(vm, 9, 16);
            const float v10 = __shfl(vm, 10, 16), v11 = __shfl(vm, 11, 16);
            const float v12 = __shfl(vm, 12, 16), v13 = __shfl(vm, 13, 16);
            const float v14 = __shfl(vm, 14, 16), v15 = __shfl(vm, 15, 16);
            // phys half0 of this thread's rows = logical half swb
            const float A0 = swb ? v8  : v0,  A1 = swb ? v9  : v1;
            const float A2 = swb ? v10 : v2,  A3 = swb ? v11 : v3;
            const float A4 = swb ? v12 : v4,  A5 = swb ? v13 : v5;
            const float A6 = swb ? v14 : v6,  A7 = swb ? v15 : v7;
            const float B0 = swb ? v0  : v8,  B1 = swb ? v1  : v9;
            const float B2 = swb ? v2  : v10, B3 = swb ? v3  : v11;
            const float B4 = swb ? v4  : v12, B5 = swb ? v5  : v13;
            const float B6 = swb ? v6  : v14, B7 = swb ? v7  : v15;
#define ROW(i, dst) {                                                         \
            const uint4 da = *(const uint4*)&uhT[(i) << 3];                   \
            const uint4 db = *(const uint4*)&uhT[((i) << 3) + 4];             \
            dst += bf_lo(da.x)*A0 + bf_hi(da.x)*A1 + bf_lo(da.y)*A2          \
                 + bf_hi(da.y)*A3 + bf_lo(da.z)*A4 + bf_hi(da.z)*A5          \
                 + bf_lo(da.w)*A6 + bf_hi(da.w)*A7                           \
                 + bf_lo(db.x)*B0 + bf_hi(db.x)*B1 + bf_lo(db.y)*B2          \
                 + bf_hi(db.y)*B3 + bf_lo(db.z)*B4 + bf_hi(db.z)*B5          \
                 + bf_lo(db.w)*B6 + bf_hi(db.w)*B7; }
            ROW(tt, L0)
            ROW(tt + 256, L1)
            ROW(tt + 512, L2)
            ROW(tt + 768, L3)
            if (has5) { ROW(tt + 1024, L4) }
#undef ROW
        }
    }
}

extern "C" void kernel_launch(void* const* d_in, const int* in_sizes, int n_in,
                              void* d_out, int out_size, void* d_ws, size_t ws_size,
                              hipStream_t stream) {
    const float* u = (const float*)d_in[0];
    const float* W = (const float*)d_in[1];
    float* out = (float*)d_out;

    const size_t shmem = (size_t)(2 * IC * 8) * 4 + 2 * IC * 2 + 128 * 4 + 16 * 4;  // 78912 B
    hipFuncSetAttribute((const void*)caps_route_kernel,
                        hipFuncAttributeMaxDynamicSharedMemorySize, (int)shmem);

    caps_route_kernel<<<(NB / 2) * OC, 512, shmem, stream>>>(u, W, out);
}

// Round 7
// 128.863 us; speedup vs baseline: 1.9920x; 1.1226x over previous
//
#include <hip/hip_runtime.h>
#include <hip/hip_bf16.h>
#include <math.h>

// CapsNet dynamic routing. R7: ONE barrier total; one wave = one batch routing.
// - 512-thread blocks own (j, 4 batches): W L2 traffic 755 -> 377 MB (~11 us
//   L2 floor). Grid 640. LDS: 4 bf16 uhat tiles + bf16 cexp = 156.7 KB,
//   1 block/CU.
// - Phase A: all 8 waves cooperate (memory-bound, no barriers inside).
// - Routing: waves 0-3 each own one batch END-TO-END. All reductions are
//   intra-wave shfl_xor; cexp round-trips through LDS within the same wave
//   (lgkmcnt only, compiler-inserted). Zero __syncthreads after Phase A.
// - s-pass partition lane=(m-quad, row mod 16): conflict-free b64 reads.
//   b-update keeps R6 half-XOR swizzle; e=(i>>2)&1 is lane-constant in all
//   passes. softmax stays max-free (|logit|<~25, f32-safe; R6 verified).
//
// u: [256][1152][8] f32; weight: [1152][10][8][16] f32; out: [256][10][16] f32

#define IC 1152
#define OC 10
#define OD 16
#define NB 256

__device__ __forceinline__ float bf_lo(unsigned w) { return __uint_as_float(w << 16); }
__device__ __forceinline__ float bf_hi(unsigned w) { return __uint_as_float(w & 0xFFFF0000u); }
__device__ __forceinline__ unsigned pack2(float a, float b) {
    __hip_bfloat162 h = __float22bfloat162_rn(make_float2(a, b));
    return *(unsigned*)&h;
}
__device__ __forceinline__ unsigned short pack1(float a) {
    __hip_bfloat16 h = __float2bfloat16(a);
    return *(unsigned short*)&h;
}

__global__ __launch_bounds__(512, 2)
void caps_route_kernel(const float* __restrict__ u,
                       const float* __restrict__ W,
                       float* __restrict__ out) {
    extern __shared__ unsigned smem_u[];
    unsigned* uh = smem_u;                                    // 4 tiles * IC*8 dwords (147456 B)
    unsigned short* ce = (unsigned short*)(uh + 4 * IC * 8);  // 4 * IC bf16 (9216 B)

    const int t  = threadIdx.x;
    const int bx = blockIdx.x;

    // XCD-aware (j, batch-quad) mapping (xcd = bx & 7 heuristic): each XCD
    // touches <=2 W j-slices (1.18 MB < 4 MB L2).
    int x = bx & 7, sg = bx >> 3;
    int j, p;
    if (sg < 64) { j = x; p = sg; }
    else { int s2 = sg - 64; j = 8 + (x >> 2); p = ((x & 3) << 4) + s2; }
    const int bb = p * 4;  // batches bb..bb+3

    // ---- Phase A: uhat[B][i][m] = sum_n u[bb+B,i,n] * W[i,j,n,m] -> LDS bf16 ----
    {
        const int q  = t & 3;            // m-quad
        const int i0 = t >> 2;           // 0..127; (i>>2)&1 k-independent (i=i0+128k)
        const int pb = (((q >> 1) ^ ((i0 >> 2) & 1)) << 2) + ((q & 1) << 1);
        const float* uptr = u + (size_t)bb * (IC * 8);
#pragma unroll 3
        for (int k = 0; k < 9; ++k) {
            const int i = i0 + 128 * k;
            const float4* wrow = (const float4*)(W + ((size_t)(i * OC + j) << 7)) + q;
            const float* urow = uptr + i * 8;
            const float4 a0 = *(const float4*)(urow);
            const float4 a1 = *(const float4*)(urow + 4);
            const float4 b0 = *(const float4*)(urow + IC * 8);
            const float4 b1 = *(const float4*)(urow + IC * 8 + 4);
            const float4 c0 = *(const float4*)(urow + 2 * IC * 8);
            const float4 c1 = *(const float4*)(urow + 2 * IC * 8 + 4);
            const float4 d0 = *(const float4*)(urow + 3 * IC * 8);
            const float4 d1 = *(const float4*)(urow + 3 * IC * 8 + 4);
            float4 sA = {0.f,0.f,0.f,0.f}, sB = {0.f,0.f,0.f,0.f};
            float4 sC = {0.f,0.f,0.f,0.f}, sD = {0.f,0.f,0.f,0.f};
            float4 w4;
#define ST(n, fA, fB, fC, fD)                                             \
            w4 = wrow[(n) * 4];                                           \
            sA.x += (fA)*w4.x; sA.y += (fA)*w4.y; sA.z += (fA)*w4.z; sA.w += (fA)*w4.w; \
            sB.x += (fB)*w4.x; sB.y += (fB)*w4.y; sB.z += (fB)*w4.z; sB.w += (fB)*w4.w; \
            sC.x += (fC)*w4.x; sC.y += (fC)*w4.y; sC.z += (fC)*w4.z; sC.w += (fC)*w4.w; \
            sD.x += (fD)*w4.x; sD.y += (fD)*w4.y; sD.z += (fD)*w4.z; sD.w += (fD)*w4.w;
            ST(0, a0.x, b0.x, c0.x, d0.x) ST(1, a0.y, b0.y, c0.y, d0.y)
            ST(2, a0.z, b0.z, c0.z, d0.z) ST(3, a0.w, b0.w, c0.w, d0.w)
            ST(4, a1.x, b1.x, c1.x, d1.x) ST(5, a1.y, b1.y, c1.y, d1.y)
            ST(6, a1.z, b1.z, c1.z, d1.z) ST(7, a1.w, b1.w, c1.w, d1.w)
#undef ST
            const int dst = (i << 3) + pb;
            *(uint2*)&uh[dst]              = make_uint2(pack2(sA.x, sA.y), pack2(sA.z, sA.w));
            *(uint2*)&uh[IC * 8 + dst]     = make_uint2(pack2(sB.x, sB.y), pack2(sB.z, sB.w));
            *(uint2*)&uh[2 * IC * 8 + dst] = make_uint2(pack2(sC.x, sC.y), pack2(sC.z, sC.w));
            *(uint2*)&uh[3 * IC * 8 + dst] = make_uint2(pack2(sD.x, sD.y), pack2(sD.z, sD.w));
        }
    }

    __syncthreads();  // THE barrier (only one in the kernel)

    const int wv = t >> 6;
    if (wv >= 4) return;  // waves 4-7 done; waves 0-3: one batch each

    const int lane = t & 63;
    unsigned* uhT = uh + wv * (IC * 8);
    unsigned short* ceT = ce + wv * IC;

    // s-pass identity: lane = (mq = lane&3, h = lane>>2); rows i = 16k+h.
    const int mq = lane & 3;
    const int h  = lane >> 2;
    const int eS = (h >> 2) & 1;                 // (i>>2)&1 for i=16k+h
    const int pbS = (((mq >> 1) ^ eS) << 2) + ((mq & 1) << 1);
    // b-update rows i = lane+64k: e = (lane>>2)&1, lane-constant.
    const bool eB = ((lane >> 2) & 1) != 0;

    float L[18];
#pragma unroll
    for (int k = 0; k < 18; ++k) L[k] = 0.f;

    for (int r = 0; r < 3; ++r) {
        float inv;
        if (r == 0) {
            inv = 1.0f / (float)IC;  // softmax(0) exactly uniform
        } else {
            float ls = 0.f;
#pragma unroll
            for (int k = 0; k < 18; ++k) {
                const float ev = __expf(L[k]);
                ceT[lane + 64 * k] = pack1(ev);
                ls += ev;
            }
#pragma unroll
            for (int o = 32; o >= 1; o >>= 1) ls += __shfl_xor(ls, o, 64);
            inv = 1.0f / ls;
        }

        // ---- s-pass: acc[d] = sum_{i=16k+h} c[i]*uhat[i][4mq+d], b64 reads ----
        float4 acc = {0.f, 0.f, 0.f, 0.f};
        if (r == 0) {
#pragma unroll 8
            for (int k = 0; k < 72; ++k) {
                const int i = 16 * k + h;
                const uint2 d = *(const uint2*)&uhT[(i << 3) + pbS];
                acc.x += bf_lo(d.x); acc.y += bf_hi(d.x);
                acc.z += bf_lo(d.y); acc.w += bf_hi(d.y);
            }
        } else {
#pragma unroll 8
            for (int k = 0; k < 72; ++k) {
                const int i = 16 * k + h;
                const uint2 d = *(const uint2*)&uhT[(i << 3) + pbS];
                const float c = __uint_as_float(((unsigned)ceT[i]) << 16);
                acc.x += c * bf_lo(d.x); acc.y += c * bf_hi(d.x);
                acc.z += c * bf_lo(d.y); acc.w += c * bf_hi(d.y);
            }
        }
        // reduce over h (lane bits 2..5)
#pragma unroll
        for (int o = 4; o <= 32; o <<= 1) {
            acc.x += __shfl_xor(acc.x, o, 64);
            acc.y += __shfl_xor(acc.y, o, 64);
            acc.z += __shfl_xor(acc.z, o, 64);
            acc.w += __shfl_xor(acc.w, o, 64);
        }
        acc.x *= inv; acc.y *= inv; acc.z *= inv; acc.w *= inv;

        // ---- squash ----
        float p2 = acc.x * acc.x + acc.y * acc.y + acc.z * acc.z + acc.w * acc.w;
        p2 += __shfl_xor(p2, 1, 64);
        p2 += __shfl_xor(p2, 2, 64);   // sum over mq quads
        const float sc = p2 / ((1.0f + p2) * sqrtf(p2 + 1e-8f));
        const float4 vq = make_float4(acc.x * sc, acc.y * sc, acc.z * sc, acc.w * sc);

        if (r == 2) {
            if (h == 0)  // lanes 0..3 write their quad
                *(float4*)&out[((size_t)(bb + wv) * OC + j) * OD + (mq << 2)] = vq;
        } else {
            // broadcast v quads (width-4 shuffles: group = same h, mq 0..3)
            const float4 q0 = make_float4(__shfl(vq.x, 0, 4), __shfl(vq.y, 0, 4),
                                          __shfl(vq.z, 0, 4), __shfl(vq.w, 0, 4));
            const float4 q1 = make_float4(__shfl(vq.x, 1, 4), __shfl(vq.y, 1, 4),
                                          __shfl(vq.z, 1, 4), __shfl(vq.w, 1, 4));
            const float4 q2 = make_float4(__shfl(vq.x, 2, 4), __shfl(vq.y, 2, 4),
                                          __shfl(vq.z, 2, 4), __shfl(vq.w, 2, 4));
            const float4 q3 = make_float4(__shfl(vq.x, 3, 4), __shfl(vq.y, 3, 4),
                                          __shfl(vq.z, 3, 4), __shfl(vq.w, 3, 4));
            // phys dwords 0-3 hold quads (eB? 2,3 : 0,1); dwords 4-7 the others
            const float4 Qa0 = eB ? q2 : q0, Qa1 = eB ? q3 : q1;
            const float4 Qb0 = eB ? q0 : q2, Qb1 = eB ? q1 : q3;
            // ---- b-update: L[k] += v . uhat[lane+64k][:] ----
#pragma unroll
            for (int k = 0; k < 18; ++k) {
                const int i = lane + 64 * k;
                const uint4 da = *(const uint4*)&uhT[i << 3];
                const uint4 db = *(const uint4*)&uhT[(i << 3) + 4];
                L[k] += bf_lo(da.x)*Qa0.x + bf_hi(da.x)*Qa0.y
                      + bf_lo(da.y)*Qa0.z + bf_hi(da.y)*Qa0.w
                      + bf_lo(da.z)*Qa1.x + bf_hi(da.z)*Qa1.y
                      + bf_lo(da.w)*Qa1.z + bf_hi(da.w)*Qa1.w
                      + bf_lo(db.x)*Qb0.x + bf_hi(db.x)*Qb0.y
                      + bf_lo(db.y)*Qb0.z + bf_hi(db.y)*Qb0.w
                      + bf_lo(db.z)*Qb1.x + bf_hi(db.z)*Qb1.y
                      + bf_lo(db.w)*Qb1.z + bf_hi(db.w)*Qb1.w;
            }
        }
    }
}

extern "C" void kernel_launch(void* const* d_in, const int* in_sizes, int n_in,
                              void* d_out, int out_size, void* d_ws, size_t ws_size,
                              hipStream_t stream) {
    const float* u = (const float*)d_in[0];
    const float* W = (const float*)d_in[1];
    float* out = (float*)d_out;

    const size_t shmem = (size_t)(4 * IC * 8) * 4 + (size_t)(4 * IC) * 2;  // 156672 B
    hipFuncSetAttribute((const void*)caps_route_kernel,
                        hipFuncAttributeMaxDynamicSharedMemorySize, (int)shmem);

    caps_route_kernel<<<(NB / 4) * OC, 512, shmem, stream>>>(u, W, out);
}